// Round 15
// baseline (92.070 us; speedup 1.0000x reference)
//
#include <hip/hip_runtime.h>

typedef float v2f __attribute__((ext_vector_type(2)));

#define NQ 12
#define NSTATES 4096          // 2^12
#define NLAYERS 4
#define NGATES 48             // 12 merged (RY·Rot_l0) + 3*12 Rot
#define NMERGED 12            // merged gates folded into product-state init
#define NGROUPS 9             // butterfly passes over gates 12..47, 4 per pass
#define TPB 256

// ---------------------------------------------------------------------------
// CNOTs are never executed: GF(2) map A with phys[j] == ref[A*j].
// CNOT(c,t): rows[bt]^=rows[bc] (rows of A), bcols[bc]^=bcols[bt] (cols of
// A^-1). 1q gate on logical bit b pairs phys {j, j^bcols[b]}, |0>-role where
// parity(j & rows[b])==0.  Z_w sign = (-1)^parity(j & rows[11-w]).
// The 12 merged RY+Rot_l0 gates act on |0...0> BEFORE any CNOT -> product
// state, built directly (~150 fma); butterfly passes cover gates 12..47.
// r13/r14 HW: 256thr/16amp/9pass == 512thr/8amp/12pass (~38-42us) -> TLP
// exhausted. This round: packed-f32 butterflies (v_pk_fma_f32 via float2
// elementwise ops): n0 = ur*x + ui*Jx + vr*y + vi*Jy, J((a,b))=(-b,a);
// halves VALU issue count of the dominant gate math.
// ---------------------------------------------------------------------------
struct Sched { unsigned m[NGATES]; unsigned sel[NGATES]; unsigned zrow[NQ]; };

constexpr Sched make_sched() {
    Sched s{};
    unsigned rows[NQ] = {}, bcols[NQ] = {};
    for (int b = 0; b < NQ; ++b) { rows[b] = 1u << b; bcols[b] = 1u << b; }
    int g = 0;
    for (int w = 0; w < NQ; ++w) { int b = NQ - 1 - w; s.m[g] = bcols[b]; s.sel[g] = rows[b]; ++g; }
    for (int l = 0; l < NLAYERS; ++l) {
        if (l > 0)
            for (int w = 0; w < NQ; ++w) { int b = NQ - 1 - w; s.m[g] = bcols[b]; s.sel[g] = rows[b]; ++g; }
        int r = (l % (NQ - 1)) + 1;
        for (int w = 0; w < NQ; ++w) {
            int c = w, t = (w + r) % NQ;
            int bc = NQ - 1 - c, bt = NQ - 1 - t;
            rows[bt] ^= rows[bc];
            bcols[bc] ^= bcols[bt];
        }
    }
    for (int w = 0; w < NQ; ++w) s.zrow[w] = rows[NQ - 1 - w];
    return s;
}

// LDS slot swizzle: fold high nibbles into the bank nibble; GF(2)-linear.
// HW-verified (r7/r9): SQ_LDS_BANK_CONFLICT ~0.5% of ds ops.
constexpr unsigned swz(unsigned j) { return j ^ (((j >> 4) ^ (j >> 8)) & 0xFu); }

struct Group {
    unsigned sel[4];
    unsigned swzc[16];
    unsigned cparbits[4];
    int npos[8];
};
struct Plan {
    Group g[NGROUPS];
    unsigned zrow[NQ];
    unsigned zparbits[NQ];
};

constexpr bool inv4(const unsigned m[4], int p0, int p1, int p2, int p3) {
    int pv[4] = {p0, p1, p2, p3};
    unsigned rows[4] = {};
    for (int i = 0; i < 4; ++i) {
        unsigned r = 0;
        for (int k = 0; k < 4; ++k) r |= ((m[i] >> pv[k]) & 1u) << k;
        rows[i] = r;
    }
    unsigned used = 0; int rank = 0;
    for (int c = 0; c < 4; ++c) {
        int pr = -1;
        for (int r = 0; r < 4; ++r)
            if (!((used >> r) & 1u) && ((rows[r] >> c) & 1u)) { pr = r; break; }
        if (pr < 0) continue;
        used |= 1u << pr; ++rank;
        for (int r = 0; r < 4; ++r)
            if (r != pr && ((rows[r] >> c) & 1u)) rows[r] ^= rows[pr];
    }
    return rank == 4;
}

constexpr int popc12(unsigned v) { int c = 0; for (int i = 0; i < 12; ++i) c += (v >> i) & 1; return c; }
constexpr int msb12(unsigned v) { int m = -1; for (int i = 0; i < 12; ++i) if ((v >> i) & 1) m = i; return m; }

constexpr int coverage(const int piv[4]) {
    bool isp[12] = {};
    for (int i = 0; i < 4; ++i) isp[piv[i]] = true;
    bool seen[4] = {}; int cov = 0, cnt = 0;
    for (int p = 0; p < 12 && cnt < 6; ++p)
        if (!isp[p]) { if (!seen[p & 3]) { seen[p & 3] = true; ++cov; } ++cnt; }
    return cov;
}

constexpr Plan make_plan() {
    Sched s = make_sched();
    Plan pl{};
    for (int w = 0; w < NQ; ++w) pl.zrow[w] = s.zrow[w];
    for (int gi = 0; gi < NGROUPS; ++gi) {
        Group &G = pl.g[gi];
        unsigned m[4] = {};
        for (int i = 0; i < 4; ++i) {
            m[i] = s.m[NMERGED + gi * 4 + i];
            G.sel[i] = s.sel[NMERGED + gi * 4 + i];
        }
        int piv[4] = {};
        unsigned bas[4] = {};
        for (int i = 0; i < 4; ++i) {
            unsigned v = m[i];
            for (int k = 0; k < i; ++k) if ((v >> piv[k]) & 1u) v ^= bas[k];
            piv[i] = msb12(v);
            bas[i] = v;
        }
        if (coverage(piv) < 4) {
            int best[4] = {piv[0], piv[1], piv[2], piv[3]};
            int bestcov = coverage(piv);
            for (int a = 0; a < 4 && bestcov < 4; ++a) {
                for (int q = 0; q < 12 && bestcov < 4; ++q) {
                    bool dup = false;
                    for (int i = 0; i < 4; ++i) if (piv[i] == q) dup = true;
                    if (dup) continue;
                    int cand[4] = {piv[0], piv[1], piv[2], piv[3]};
                    cand[a] = q;
                    if (!inv4(m, cand[0], cand[1], cand[2], cand[3])) continue;
                    int cv = coverage(cand);
                    if (cv > bestcov) { bestcov = cv; for (int i = 0; i < 4; ++i) best[i] = cand[i]; }
                }
            }
            for (int i = 0; i < 4; ++i) piv[i] = best[i];
        }
        {
            bool isp[12] = {};
            for (int i = 0; i < 4; ++i) isp[piv[i]] = true;
            int k = 0;
            for (int p = 0; p < 12; ++p) if (!isp[p]) G.npos[k++] = p;
        }
        for (int e = 0; e < 16; ++e) {
            unsigned c = 0;
            for (int q = 0; q < 4; ++q) if ((e >> q) & 1) c ^= m[q];
            G.swzc[e] = swz(c);
        }
        for (int i = 0; i < 4; ++i) {
            unsigned bits = 0;
            for (int e = 0; e < 16; ++e) {
                unsigned c = 0;
                for (int q = 0; q < 4; ++q) if ((e >> q) & 1) c ^= m[q];
                if (popc12(c & G.sel[i]) & 1) bits |= 1u << e;
            }
            G.cparbits[i] = bits;
        }
        if (gi == NGROUPS - 1) {
            for (int w = 0; w < NQ; ++w) {
                unsigned bits = 0;
                for (int e = 0; e < 16; ++e) {
                    unsigned c = 0;
                    for (int q = 0; q < 4; ++q) if ((e >> q) & 1) c ^= m[q];
                    if (popc12(c & s.zrow[w]) & 1) bits |= 1u << e;
                }
                pl.zparbits[w] = bits;
            }
        }
    }
    return pl;
}

__device__ constexpr Plan PLAN = make_plan();

__device__ __forceinline__ float xorf(float a, unsigned s) {
    return __uint_as_float(__float_as_uint(a) ^ s);
}

// Packed butterfly: x,y are (re,im) float2 vectors. With J((a,b)) = (-b,a):
//   n0 = ur*x + uis*Jx + vrs*y + vi*Jy
//   n1 = ur*y - uis*Jy - vrs*x + vi*Jx
// Elementwise v2f ops compile to v_pk_fma_f32 / v_pk_mul_f32 (VOP3P); the
// J swap+neg folds into op_sel/neg source modifiers.
#define BFLY2(ip, e, f)                                                       \
    {                                                                         \
        const bool neg = ((G.cparbits[ip] >> (e)) & 1u) != 0;                 \
        const float uis = neg ? ui_n : ui_p;                                  \
        const float vrs = neg ? vr_n : vr_p;                                  \
        const v2f x = a[e], y = a[f];                                         \
        const v2f Jx = {-x.y, x.x};                                           \
        const v2f Jy = {-y.y, y.x};                                           \
        a[e] = x * ur + Jx * uis + y * vrs + Jy * vi;                         \
        a[f] = y * ur - Jy * uis - x * vrs + Jx * vi;                         \
    }

// ---------------------------------------------------------------------------
// One pass (gates NMERGED+GI*4 .. +3): thread owns a 16-element XOR-coset.
// Loads split 8/8 with gate-0 butterflies interleaved. template<GI> keeps
// every mask / swizzle / parity bit an instruction immediate.
// ---------------------------------------------------------------------------
template <int GI>
__device__ __forceinline__ void do_pass(int tid, v2f (&a)[16],
                                        unsigned &jr_out, v2f* st, const float4* gmat)
{
    constexpr Group G = PLAN.g[GI];

    unsigned jr = 0;
    #pragma unroll
    for (int k = 0; k < 8; ++k) jr |= ((unsigned)(tid >> k) & 1u) << G.npos[k];
    const unsigned basev = jr ^ (((jr >> 4) ^ (jr >> 8)) & 0xFu);   // swz(jr)

    #pragma unroll
    for (int e = 0; e < 8; ++e) a[e] = st[basev ^ G.swzc[e]];

    {   // gate 0: butterflies on loaded half, overlap second-half loads
        const float4 uv = gmat[NMERGED + GI * 4 + 0];
        const unsigned sgP = (unsigned)(__popc(jr & G.sel[0]) & 1) << 31;
        const float ur = uv.x, vi = uv.w;
        const float ui_p = xorf(uv.y, sgP), ui_n = xorf(uv.y, sgP ^ 0x80000000u);
        const float vr_p = xorf(uv.z, sgP), vr_n = xorf(uv.z, sgP ^ 0x80000000u);
        BFLY2(0, 0, 1)
        BFLY2(0, 2, 3)
        BFLY2(0, 4, 5)
        BFLY2(0, 6, 7)
        #pragma unroll
        for (int e = 8; e < 16; ++e) a[e] = st[basev ^ G.swzc[e]];
        BFLY2(0, 8, 9)
        BFLY2(0, 10, 11)
        BFLY2(0, 12, 13)
        BFLY2(0, 14, 15)
    }

    #pragma unroll
    for (int i = 1; i < 4; ++i) {
        const float4 uv = gmat[NMERGED + GI * 4 + i];
        const unsigned sgP = (unsigned)(__popc(jr & G.sel[i]) & 1) << 31;
        const float ur = uv.x, vi = uv.w;
        const float ui_p = xorf(uv.y, sgP), ui_n = xorf(uv.y, sgP ^ 0x80000000u);
        const float vr_p = xorf(uv.z, sgP), vr_n = xorf(uv.z, sgP ^ 0x80000000u);
        #pragma unroll
        for (int e = 0; e < 16; ++e) {
            if (e & (1 << i)) continue;
            const int f = e | (1 << i);
            BFLY2(i, e, f)
        }
    }

    if constexpr (GI < NGROUPS - 1) {
        #pragma unroll
        for (int e = 0; e < 16; ++e)
            st[basev ^ G.swzc[e]] = a[e];
        __syncthreads();
    }
    jr_out = jr;
}

template <int GI>
__device__ __forceinline__ void run_from(int tid, v2f (&a)[16],
                                         unsigned &jr, v2f* st, const float4* gmat)
{
    do_pass<GI>(tid, a, jr, st, gmat);
    if constexpr (GI + 1 < NGROUPS) run_from<GI + 1>(tid, a, jr, st, gmat);
}

// waves_per_eu(4,4): LDS caps residency at 4 blocks/CU = 4 waves/EU; pinning
// max=4 gives the 128-VGPR budget. HW-verified r9: spill eliminated.
__global__ __launch_bounds__(TPB)
__attribute__((amdgpu_waves_per_eu(4, 4)))
void qreg_kernel(
    const float* __restrict__ x,    // (B, 12)
    const float* __restrict__ W,    // (4, 12, 3)
    const float* __restrict__ hw,   // (1, 12)
    const float* __restrict__ hb,   // (1,)
    float* __restrict__ out)        // (B,)
{
    __shared__ v2f st[NSTATES];      // 32 KB state (swizzled slots)
    __shared__ float4 gmat[NGATES];  // (ur, ui, vr, vi)
    __shared__ float red[TPB / 64];

    const int tid = threadIdx.x;
    const int b = blockIdx.x;

    // ---- gate matrices: one thread per gate -------------------------------
    if (tid < NGATES) {
        const int l = tid / NQ;
        const int w = tid % NQ;
        const float* wp = W + tid * 3;
        float phi = wp[0], th = wp[1], om = wp[2];
        float sn, cs;  sincosf(0.5f * th, &sn, &cs);
        float sa, ca;  sincosf(0.5f * (phi + om), &sa, &ca);
        float sb, cb;  sincosf(0.5f * (phi - om), &sb, &cb);
        float u2r = ca * cs, u2i = -sa * cs;
        float v2r = -cb * sn, v2i = -sb * sn;
        float ur, ui, vr, vi;
        if (l == 0) {
            float s1, c1; sincosf(0.5f * x[b * NQ + w], &s1, &c1);
            ur = u2r * c1 + v2r * s1;  ui = u2i * c1 + v2i * s1;
            vr = v2r * c1 - u2r * s1;  vi = v2i * c1 - u2i * s1;
        } else {
            ur = u2r; ui = u2i; vr = v2r; vi = v2i;
        }
        gmat[tid] = make_float4(ur, ui, vr, vi);
    }
    __syncthreads();

    v2f a[16];

    // ---- product-state init (replaces first 3 butterfly passes) -----------
    // amp(j) = prod_p f(gmat[11-p], bit_p(j)), j = (tid<<4)|e.
    // f(g,0) = (g.x, g.y); f(g,1) = (-g.z, g.w)   [= -conj(v)]
    // cmul(p, f) = fr*p + fi*Jp  (packed, 2 ops).
    {
        v2f p = {1.0f, 0.0f};
        #pragma unroll
        for (int k = 7; k >= 0; --k) {               // tid bit k -> gmat[7-k]
            const float4 g = gmat[7 - k];
            const bool bset = ((tid >> k) & 1) != 0;
            const float fr = bset ? -g.z : g.x;
            const float fi = bset ?  g.w : g.y;
            const v2f Jp = {-p.y, p.x};
            p = p * fr + Jp * fi;
        }
        v2f t2[2], t4[4], t8[8];
        {   const float4 g = gmat[8];                // e bit 3
            const v2f Jp = {-p.y, p.x};
            t2[0] = p * g.x + Jp * g.y;
            t2[1] = p * (-g.z) + Jp * g.w;
        }
        {   const float4 g = gmat[9];                // e bit 2
            #pragma unroll
            for (int h = 0; h < 2; ++h) {
                const v2f Jt = {-t2[h].y, t2[h].x};
                t4[2*h]   = t2[h] * g.x + Jt * g.y;
                t4[2*h+1] = t2[h] * (-g.z) + Jt * g.w;
            }
        }
        {   const float4 g = gmat[10];               // e bit 1
            #pragma unroll
            for (int h = 0; h < 4; ++h) {
                const v2f Jt = {-t4[h].y, t4[h].x};
                t8[2*h]   = t4[h] * g.x + Jt * g.y;
                t8[2*h+1] = t4[h] * (-g.z) + Jt * g.w;
            }
        }
        {   const float4 g = gmat[11];               // e bit 0
            #pragma unroll
            for (int h = 0; h < 8; ++h) {
                const v2f Jt = {-t8[h].y, t8[h].x};
                a[2*h]   = t8[h] * g.x + Jt * g.y;
                a[2*h+1] = t8[h] * (-g.z) + Jt * g.w;
            }
        }
        // swz((tid<<4)|e) = (tid<<4) | (e ^ hh)
        const unsigned hh = ((unsigned)tid ^ ((unsigned)tid >> 4)) & 0xFu;
        const unsigned base = (unsigned)tid << 4;
        #pragma unroll
        for (int e = 0; e < 16; ++e)
            st[base | ((unsigned)e ^ hh)] = a[e];
    }
    __syncthreads();

    // ---- 9 register-blocked passes (gates 12..47) -------------------------
    unsigned jr = 0;
    run_from<0>(tid, a, jr, st, gmat);

    // ---- fused Z expvals + linear head (state still in registers) ---------
    float hws[NQ];
    #pragma unroll
    for (int w = 0; w < NQ; ++w) {
        const unsigned sg = (unsigned)(__popc(jr & PLAN.zrow[w]) & 1) << 31;
        hws[w] = xorf(hw[w], sg);
    }
    float acc = 0.0f;
    #pragma unroll
    for (int e = 0; e < 16; ++e) {
        const float prob = fmaf(a[e].x, a[e].x, a[e].y * a[e].y);
        float coef = 0.0f;
        #pragma unroll
        for (int w = 0; w < NQ; ++w)
            coef += ((PLAN.zparbits[w] >> e) & 1u) ? -hws[w] : hws[w];
        acc = fmaf(prob, coef, acc);
    }

    #pragma unroll
    for (int o = 32; o > 0; o >>= 1) acc += __shfl_xor(acc, o, 64);
    if ((tid & 63) == 0) red[tid >> 6] = acc;
    __syncthreads();
    if (tid == 0) out[b] = red[0] + red[1] + red[2] + red[3] + hb[0];
}

extern "C" void kernel_launch(void* const* d_in, const int* in_sizes, int n_in,
                              void* d_out, int out_size, void* d_ws, size_t ws_size,
                              hipStream_t stream) {
    const float* x  = (const float*)d_in[0];   // (B, 12) float32
    const float* W  = (const float*)d_in[1];   // (4, 12, 3) float32
    const float* hw = (const float*)d_in[2];   // (1, 12) float32
    const float* hb = (const float*)d_in[3];   // (1,) float32
    float* out = (float*)d_out;                // (B,) float32

    int B = in_sizes[0] / NQ;                  // 1024
    qreg_kernel<<<B, TPB, 0, stream>>>(x, W, hw, hb, out);
}